// Round 7
// baseline (263.339 us; speedup 1.0000x reference)
//
#include <hip/hip_runtime.h>
#include <hip/hip_bf16.h>
#include <math.h>

// ---- problem constants ----
#define BB     256
#define TT     64
#define BT     (BB*TT)      // 16384 tokens
#define XD     44
#define XP     40
#define XS     10
#define HID    128
#define XEMB   32
#define NHID   8
#define NAG    10
#define NEDGE  90
#define GEMB   720          // NHID*NEDGE
#define KF     768          // padded fused feature dim
#define NTOT   640          // 128 (a) + 128 (o) + 384 (ih)

// F feature layout (v2): [0:32) xemb | [32:42) demo | [42] treat | [43:48) pad0 | [48:768) gemb

typedef __bf16  bf16_t;
typedef __bf16  bf16x4 __attribute__((ext_vector_type(4)));
typedef __bf16  bf16x8 __attribute__((ext_vector_type(8)));
typedef float   floatx4 __attribute__((ext_vector_type(4)));
typedef _Float16 half2_t __attribute__((ext_vector_type(2)));
typedef _Float16 half4_t __attribute__((ext_vector_type(4)));
typedef _Float16 half8_t __attribute__((ext_vector_type(8)));

__device__ __forceinline__ float rcp_fast(float x) { return __builtin_amdgcn_rcpf(x); }
__device__ __forceinline__ float sigmoid_fast(float v) { return rcp_fast(1.f + __expf(-v)); }
__device__ __forceinline__ float tanh_fast(float x) { return 1.f - 2.f * rcp_fast(1.f + __expf(2.f * x)); }
__device__ __forceinline__ float elu_fast(float v) { return v > 0.f ? v : __expf(v) - 1.f; }
__device__ __forceinline__ float fdot2f(half2_t a, half2_t b, float acc) {
  return __builtin_amdgcn_fdot2(a, b, acc, false);
}
__device__ __forceinline__ float dot8h(half8_t a, half8_t b, float acc) {
  acc = fdot2f(half2_t{a[0], a[1]}, half2_t{b[0], b[1]}, acc);
  acc = fdot2f(half2_t{a[2], a[3]}, half2_t{b[2], b[3]}, acc);
  acc = fdot2f(half2_t{a[4], a[5]}, half2_t{b[4], b[5]}, acc);
  acc = fdot2f(half2_t{a[6], a[7]}, half2_t{b[6], b[7]}, acc);
  return acc;
}
// LDS-only barrier: waits lgkmcnt(0) but leaves global loads/stores in flight.
__device__ __forceinline__ void lds_barrier() {
  asm volatile("s_waitcnt lgkmcnt(0)" ::: "memory");
  __builtin_amdgcn_s_barrier();
}

// ---------------------------------------------------------------------------
// Kernel 1: build Wcat^T (n-major, k-contiguous) bf16 + fused bias (fp32)
// ---------------------------------------------------------------------------
__global__ __launch_bounds__(256) void prep_kernel(
    const float* __restrict__ Wa1, const float* __restrict__ ba1,
    const float* __restrict__ Wo1, const float* __restrict__ bo1,
    const float* __restrict__ Wih, const float* __restrict__ bih,
    bf16_t* __restrict__ WT, float* __restrict__ bcat) {
  int idx = blockIdx.x * 256 + threadIdx.x;
  if (idx >= NTOT * KF) return;
  int n = idx / KF, k = idx - n * KF;
  float v = 0.f;
  if (n < 128) {                       // W_a1: a_in = [demo(10), gemb(720)]
    if (k >= 32 && k < 42)  v = Wa1[n * 730 + (k - 32)];
    else if (k >= 48)       v = Wa1[n * 730 + 10 + (k - 48)];
  } else if (n < 256) {                // W_o1: o_in = [xemb, demo, treat, gemb]
    int m = n - 128;
    if (k < 43)             v = Wo1[m * 763 + k];
    else if (k >= 48)       v = Wo1[m * 763 + 43 + (k - 48)];
  } else {                             // W_ih: rnn_in = [xemb(32), treat(1), gemb(720)]
    int m = n - 256;
    if (k < 32)             v = Wih[m * 753 + k];
    else if (k == 42)       v = Wih[m * 753 + 32];
    else if (k >= 48)       v = Wih[m * 753 + 33 + (k - 48)];
  }
  WT[n * KF + k] = (bf16_t)v;
  if (k == 0) {
    bcat[n] = (n < 128) ? ba1[n] : (n < 256 ? bo1[n - 128] : bih[n - 256]);
  }
}

// ---------------------------------------------------------------------------
// Kernel 2: encoder v3 — one wave per block, 4 tokens/block, packed-f16 dot2.
// ---------------------------------------------------------------------------
__global__ __launch_bounds__(64) void encoder_kernel(
    const float* __restrict__ x, const float* __restrict__ x_demo,
    const float* __restrict__ ftreat,
    const float* __restrict__ Wm1a, const float* __restrict__ bm1a,
    const float* __restrict__ Wm1b, const float* __restrict__ bm1b,
    const float* __restrict__ Wm2a, const float* __restrict__ bm2a,
    const float* __restrict__ Wm2b, const float* __restrict__ bm2b,
    const float* __restrict__ Wx2e, const float* __restrict__ bx2e,
    const float* __restrict__ Wst, const float* __restrict__ bst,
    bf16_t* __restrict__ F) {
  int blk = blockIdx.x;                 // 0..4095
  int b = blk >> 4, tc = blk & 15;      // batch, 4-token chunk
  int lane = threadIdx.x;

  __shared__ __align__(16) _Float16 h1sp[NAG * 8];
  __shared__ __align__(16) _Float16 w2aR[64];
  __shared__ __align__(16) _Float16 w2aS[64];
  __shared__ __align__(16) _Float16 w2bp[64];
  __shared__ float demoL[XS];

  if (lane < 8) {
    float4 v0 = *(const float4*)(Wm2a + lane * 16);
    float4 v1 = *(const float4*)(Wm2a + lane * 16 + 4);
    float4 v2 = *(const float4*)(Wm2a + lane * 16 + 8);
    float4 v3 = *(const float4*)(Wm2a + lane * 16 + 12);
    *(half8_t*)&w2aR[lane * 8] = half8_t{
        (_Float16)v0.x, (_Float16)v0.y, (_Float16)v0.z, (_Float16)v0.w,
        (_Float16)v1.x, (_Float16)v1.y, (_Float16)v1.z, (_Float16)v1.w};
    *(half8_t*)&w2aS[lane * 8] = half8_t{
        (_Float16)v2.x, (_Float16)v2.y, (_Float16)v2.z, (_Float16)v2.w,
        (_Float16)v3.x, (_Float16)v3.y, (_Float16)v3.z, (_Float16)v3.w};
    float4 u0 = *(const float4*)(Wm2b + lane * 8);
    float4 u1 = *(const float4*)(Wm2b + lane * 8 + 4);
    *(half8_t*)&w2bp[lane * 8] = half8_t{
        (_Float16)u0.x, (_Float16)u0.y, (_Float16)u0.z, (_Float16)u0.w,
        (_Float16)u1.x, (_Float16)u1.y, (_Float16)u1.z, (_Float16)u1.w};
  }
  if (lane < 10) {
    float s = bst[lane];
#pragma unroll
    for (int j = 0; j < 10; j++) s += x_demo[b * XS + j] * Wst[lane * 10 + j];
    demoL[lane] = s;
  }

  half4_t wA[8]; float bA[8];
  half8_t wB1[8]; float bB1[8];
  float bR[8], bG[8];
#pragma unroll
  for (int o = 0; o < 8; o++) {
    float4 v = *(const float4*)(Wm1a + o * 4);
    wA[o] = half4_t{(_Float16)v.x, (_Float16)v.y, (_Float16)v.z, (_Float16)v.w};
    bA[o] = bm1a[o];
    float4 w0 = *(const float4*)(Wm1b + o * 8);
    float4 w1 = *(const float4*)(Wm1b + o * 8 + 4);
    wB1[o] = half8_t{(_Float16)w0.x, (_Float16)w0.y, (_Float16)w0.z, (_Float16)w0.w,
                     (_Float16)w1.x, (_Float16)w1.y, (_Float16)w1.z, (_Float16)w1.w};
    bB1[o] = bm1b[o];
    bR[o] = bm2a[o];
    bG[o] = bm2b[o];
  }
  half4_t wX; float bX;
  {
    float4 v = *(const float4*)(Wx2e + (lane & 31) * 4);
    wX = half4_t{(_Float16)v.x, (_Float16)v.y, (_Float16)v.z, (_Float16)v.w};
    bX = bx2e[lane & 31];
  }
  __syncthreads();
  float demov = (lane >= 32 && lane < 42) ? demoL[lane - 32] : 0.f;

  for (int ti = 0; ti < 4; ti++) {
    int t = tc * 4 + ti;
    int tok = b * TT + t;
    const float* row = x + (size_t)(b * 65 + t) * XD;
    bf16_t* Frow = F + (size_t)tok * KF;

    if (lane < NAG) {
      float4 xa = *(const float4*)(row + lane * 4);
      half2_t x0{(_Float16)xa.x, (_Float16)xa.y};
      half2_t x1{(_Float16)xa.z, (_Float16)xa.w};
      float h1v[8];
#pragma unroll
      for (int o = 0; o < 8; o++) {
        float s = bA[o];
        s = fdot2f(x0, half2_t{wA[o][0], wA[o][1]}, s);
        s = fdot2f(x1, half2_t{wA[o][2], wA[o][3]}, s);
        h1v[o] = elu_fast(s);
      }
      half2_t e0{(_Float16)h1v[0], (_Float16)h1v[1]};
      half2_t e1{(_Float16)h1v[2], (_Float16)h1v[3]};
      half2_t e2{(_Float16)h1v[4], (_Float16)h1v[5]};
      half2_t e3{(_Float16)h1v[6], (_Float16)h1v[7]};
      half8_t hout;
#pragma unroll
      for (int o = 0; o < 8; o++) {
        float s = bB1[o];
        s = fdot2f(e0, half2_t{wB1[o][0], wB1[o][1]}, s);
        s = fdot2f(e1, half2_t{wB1[o][2], wB1[o][3]}, s);
        s = fdot2f(e2, half2_t{wB1[o][4], wB1[o][5]}, s);
        s = fdot2f(e3, half2_t{wB1[o][6], wB1[o][7]}, s);
        hout[o] = (_Float16)elu_fast(s);
      }
      *(half8_t*)&h1sp[lane * 8] = hout;
    }
    __syncthreads();

#pragma unroll
    for (int q = 0; q < 2; q++) {
      int e = lane + 64 * q;
      if (e < NEDGE) {
        int r = (e * 57) >> 9;               // e/9 for e<90
        int sd = e - 9 * r;
        sd += (sd >= r) ? 1 : 0;
        half8_t hr = *(const half8_t*)&h1sp[r * 8];
        half8_t hs = *(const half8_t*)&h1sp[sd * 8];
        float av[8];
#pragma unroll
        for (int o = 0; o < 8; o++) {
          half8_t wr8 = *(const half8_t*)&w2aR[o * 8];
          half8_t ws8 = *(const half8_t*)&w2aS[o * 8];
          float s = bR[o];
          s = dot8h(hr, wr8, s);
          s = dot8h(hs, ws8, s);
          av[o] = elu_fast(s);
        }
        half2_t a0{(_Float16)av[0], (_Float16)av[1]};
        half2_t a1{(_Float16)av[2], (_Float16)av[3]};
        half2_t a2{(_Float16)av[4], (_Float16)av[5]};
        half2_t a3{(_Float16)av[6], (_Float16)av[7]};
        union { bf16_t h[8]; uint4 u; } pk;
#pragma unroll
        for (int o = 0; o < 8; o++) {
          half8_t wb8 = *(const half8_t*)&w2bp[o * 8];
          float s = bG[o];
          s = fdot2f(a0, half2_t{wb8[0], wb8[1]}, s);
          s = fdot2f(a1, half2_t{wb8[2], wb8[3]}, s);
          s = fdot2f(a2, half2_t{wb8[4], wb8[5]}, s);
          s = fdot2f(a3, half2_t{wb8[6], wb8[7]}, s);
          pk.h[o] = (bf16_t)elu_fast(s);
        }
        *(uint4*)(Frow + 48 + e * 8) = pk.u;
      }
    }

    float4 xe = *(const float4*)(row + XP);
    if (lane < 32) {
      float s = bX;
      s = fdot2f(half2_t{(_Float16)xe.x, (_Float16)xe.y}, half2_t{wX[0], wX[1]}, s);
      s = fdot2f(half2_t{(_Float16)xe.z, (_Float16)xe.w}, half2_t{wX[2], wX[3]}, s);
      Frow[lane] = (bf16_t)s;
    } else if (lane < 42) {
      Frow[lane] = (bf16_t)demov;
    } else if (lane == 42) {
      Frow[42] = (bf16_t)ftreat[b * 65 + t];
    } else if (lane < 48) {
      Frow[lane] = (bf16_t)0.f;
    }
    __syncthreads();
  }
}

// ---------------------------------------------------------------------------
// Kernel 3: G[16384,640] = F[16384,768] @ WT^T + bcat  (bf16 MFMA, fp32 acc)
// ---------------------------------------------------------------------------
__global__ __launch_bounds__(256) void gemm_kernel(
    const bf16_t* __restrict__ F, const bf16_t* __restrict__ WT,
    const float* __restrict__ bcat, float* __restrict__ G) {
  __shared__ __align__(16) bf16_t As[128 * 32];
  __shared__ __align__(16) bf16_t Bs[128 * 32];

  int tid  = threadIdx.x;
  int lane = tid & 63;
  int wv   = tid >> 6;
  int wr   = wv >> 1, wc = wv & 1;
  int m0 = blockIdx.x * 128, n0 = blockIdx.y * 128;

  floatx4 acc[4][4];
#pragma unroll
  for (int i = 0; i < 4; i++)
#pragma unroll
    for (int j = 0; j < 4; j++) acc[i][j] = floatx4{0.f, 0.f, 0.f, 0.f};

  int c0 = tid, c1 = tid + 256;
  int r0 = c0 >> 2, p0 = c0 & 3;
  int r1 = c1 >> 2, p1 = c1 & 3;
  int qr = lane >> 4;
  int lr = lane & 15;

  for (int k0 = 0; k0 < KF; k0 += 32) {
    uint4 a0 = *(const uint4*)(F  + (size_t)(m0 + r0) * KF + k0 + p0 * 8);
    uint4 a1 = *(const uint4*)(F  + (size_t)(m0 + r1) * KF + k0 + p1 * 8);
    uint4 b0 = *(const uint4*)(WT + (size_t)(n0 + r0) * KF + k0 + p0 * 8);
    uint4 b1 = *(const uint4*)(WT + (size_t)(n0 + r1) * KF + k0 + p1 * 8);
    __syncthreads();
    ((uint4*)As)[c0] = a0; ((uint4*)As)[c1] = a1;
    ((uint4*)Bs)[c0] = b0; ((uint4*)Bs)[c1] = b1;
    __syncthreads();

    bf16x8 af[4], bf[4];
#pragma unroll
    for (int i = 0; i < 4; i++) {
      af[i] = *(const bf16x8*)(As + (wr * 64 + i * 16 + lr) * 32 + qr * 8);
      bf[i] = *(const bf16x8*)(Bs + (wc * 64 + i * 16 + lr) * 32 + qr * 8);
    }
#pragma unroll
    for (int i = 0; i < 4; i++)
#pragma unroll
      for (int j = 0; j < 4; j++)
        acc[i][j] = __builtin_amdgcn_mfma_f32_16x16x32_bf16(af[i], bf[j], acc[i][j], 0, 0, 0);
  }

#pragma unroll
  for (int i = 0; i < 4; i++) {
#pragma unroll
    for (int j = 0; j < 4; j++) {
      int col = n0 + wc * 64 + j * 16 + lr;
      float bv = bcat[col];
#pragma unroll
      for (int r = 0; r < 4; r++) {
        int row = m0 + wr * 64 + i * 16 + qr * 4 + r;
        G[(size_t)row * NTOT + col] = acc[i][j][r] + bv;
      }
    }
  }
}

// ---------------------------------------------------------------------------
// Kernel 4: heads — a_out / y_out (one wave per token)
// ---------------------------------------------------------------------------
__global__ __launch_bounds__(256) void head_kernel(
    const float* __restrict__ G, const float* __restrict__ Wa2,
    const float* __restrict__ Wo2, float* __restrict__ out) {
  int wid  = (blockIdx.x * 256 + threadIdx.x) >> 6;
  int lane = threadIdx.x & 63;
  const float* g = G + (size_t)wid * NTOT;
  float sa = fmaxf(g[lane], 0.f) * Wa2[lane] + fmaxf(g[lane + 64], 0.f) * Wa2[lane + 64];
  float sy = fmaxf(g[128 + lane], 0.f) * Wo2[lane] + fmaxf(g[192 + lane], 0.f) * Wo2[lane + 64];
#pragma unroll
  for (int off = 32; off > 0; off >>= 1) {
    sa += __shfl_down(sa, off, 64);
    sy += __shfl_down(sy, off, 64);
  }
  if (lane == 0) {
    out[(size_t)wid * 130 + 0] = sa;
    out[(size_t)wid * 130 + 1] = sy;
  }
}

// ---------------------------------------------------------------------------
// Kernel 5: GRU v4 — MFMA-batched. 16 blocks x 256 threads; block owns 16
// sequences. Per step: gh(384x16) = Whh(384x128) @ h^T(128x16) as 96
// mfma_f32_16x16x32_bf16 (24/wave). Whh lives in 96 A-fragment VGPRs/lane
// (loaded once; MFMA can read AGPRs directly, so allocator placement is
// cost-free). Wave w owns units [w*32,(w+1)*32) for all 3 gates, so each
// lane's r/z/n accumulators align and gates are computed locally:
//   lane = seq (col), rows = 4 consecutive units -> gi loads are float4,
//   h writes ds_write_b64, out stores float2. One lgkm-only barrier/step.
// h tile: double-buffered [16][136] bf16 (pad->2-way conflicts only).
// Bias folded into the per-step accumulator init.
// ---------------------------------------------------------------------------
__global__ __launch_bounds__(256, 1) void gru_kernel(
    const float* __restrict__ G, const float* __restrict__ h0,
    const float* __restrict__ Whh, const float* __restrict__ bhh,
    float* __restrict__ out) {
  int tid  = threadIdx.x;
  int w    = tid >> 6;          // wave 0..3
  int lane = tid & 63;
  int l15  = lane & 15;         // sequence within block
  int quad = lane >> 4;
  int b0   = blockIdx.x * 16;
  int s    = b0 + l15;          // this lane's sequence

  __shared__ __align__(16) bf16_t hT[2][16 * 136];   // [buf][seq*136 + unit]

  // ---- static per-lane state ----
  // A-fragments of Whh: i = g*2+tp, rows g*128 + w*32 + tp*16 + l15
  bf16x8 afrag[6][4];
#pragma unroll
  for (int g = 0; g < 3; g++) {
#pragma unroll
    for (int tp = 0; tp < 2; tp++) {
      const float* wrow = Whh + (size_t)(g * 128 + w * 32 + tp * 16 + l15) * HID + quad * 8;
#pragma unroll
      for (int ks = 0; ks < 4; ks++) {
        float4 a = *(const float4*)(wrow + ks * 32);
        float4 b = *(const float4*)(wrow + ks * 32 + 4);
        afrag[g * 2 + tp][ks] = bf16x8{
            (bf16_t)a.x, (bf16_t)a.y, (bf16_t)a.z, (bf16_t)a.w,
            (bf16_t)b.x, (bf16_t)b.y, (bf16_t)b.z, (bf16_t)b.w};
      }
    }
  }
  // bias (folded into acc init): i = g*2+tp -> units g*128 + jb(tp) + 0..3
  int jb0 = w * 32 + quad * 4;          // tp=0 unit base (within 0..127)
  int jb1 = jb0 + 16;                   // tp=1
  floatx4 biasv[6];
#pragma unroll
  for (int g = 0; g < 3; g++) {
    biasv[g * 2 + 0] = *(const floatx4*)(bhh + g * 128 + jb0);
    biasv[g * 2 + 1] = *(const floatx4*)(bhh + g * 128 + jb1);
  }
  // h_prev in registers: (seq s, units jb+0..3)
  floatx4 hprev[2];
  hprev[0] = *(const floatx4*)(h0 + (size_t)s * HID + jb0);
  hprev[1] = *(const floatx4*)(h0 + (size_t)s * HID + jb1);

  // ---- initial h tile fill (seq-major bf16) ----
  {
    int sq = tid >> 4, u = (tid & 15) * 8;
    const float* hr = h0 + (size_t)(b0 + sq) * HID + u;
    float4 a = *(const float4*)hr;
    float4 b = *(const float4*)(hr + 4);
    *(bf16x8*)&hT[0][sq * 136 + u] = bf16x8{
        (bf16_t)a.x, (bf16_t)a.y, (bf16_t)a.z, (bf16_t)a.w,
        (bf16_t)b.x, (bf16_t)b.y, (bf16_t)b.z, (bf16_t)b.w};
  }
  // ---- initial gi load (t=0) ----
  const float* grow = G + (size_t)s * TT * NTOT;   // advance by NTOT per step
  floatx4 gi[6];
#pragma unroll
  for (int g = 0; g < 3; g++) {
    gi[g * 2 + 0] = *(const floatx4*)(grow + 256 + g * 128 + jb0);
    gi[g * 2 + 1] = *(const floatx4*)(grow + 256 + g * 128 + jb1);
  }
  __syncthreads();

  float* obase = out + (size_t)s * TT * 130 + 2;   // advance by 130 per step

  for (int t = 0; t < TT; t++) {
    // B-fragments: h^T tile, n = seq = l15, k = ks*32 + quad*8
    const bf16_t* hb = &hT[t & 1][l15 * 136 + quad * 8];
    bf16x8 bfrag[4];
#pragma unroll
    for (int ks = 0; ks < 4; ks++) bfrag[ks] = *(const bf16x8*)(hb + ks * 32);

    // prefetch gi(t+1) — one full step of slack
    floatx4 ngi[6];
    if (t + 1 < TT) {
      const float* gn = grow + NTOT;
#pragma unroll
      for (int g = 0; g < 3; g++) {
        ngi[g * 2 + 0] = *(const floatx4*)(gn + 256 + g * 128 + jb0);
        ngi[g * 2 + 1] = *(const floatx4*)(gn + 256 + g * 128 + jb1);
      }
    }

    // gh = Whh @ h^T + bhh : acc init = bias, 4 K-steps, 6 independent chains
    floatx4 acc[6];
#pragma unroll
    for (int i = 0; i < 6; i++) acc[i] = biasv[i];
#pragma unroll
    for (int ks = 0; ks < 4; ks++)
#pragma unroll
      for (int i = 0; i < 6; i++)
        acc[i] = __builtin_amdgcn_mfma_f32_16x16x32_bf16(afrag[i][ks], bfrag[ks], acc[i], 0, 0, 0);

    // gates (local: r/z/n accs for unit j all live in this lane)
#pragma unroll
    for (int tp = 0; tp < 2; tp++) {
      int jb = tp ? jb1 : jb0;
      floatx4 hn;
#pragma unroll
      for (int r = 0; r < 4; r++) {
        float rr = sigmoid_fast(gi[0 + tp][r] + acc[0 + tp][r]);
        float zz = sigmoid_fast(gi[2 + tp][r] + acc[2 + tp][r]);
        float nn = tanh_fast(gi[4 + tp][r] + rr * acc[4 + tp][r]);
        hn[r] = (1.f - zz) * nn + zz * hprev[tp][r];
      }
      hprev[tp] = hn;
      // h -> next LDS buffer (4 consecutive units: one b64 write)
      *(bf16x4*)&hT[(t + 1) & 1][l15 * 136 + jb] = bf16x4{
          (bf16_t)hn[0], (bf16_t)hn[1], (bf16_t)hn[2], (bf16_t)hn[3]};
      // out store (8B-aligned float2 pairs)
      float* ob = obase + jb;
      *(float2*)ob       = float2{hn[0], hn[1]};
      *(float2*)(ob + 2) = float2{hn[2], hn[3]};
    }

    lds_barrier();
#pragma unroll
    for (int i = 0; i < 6; i++) gi[i] = ngi[i];
    grow  += NTOT;
    obase += 130;
  }
}

// ---------------------------------------------------------------------------
extern "C" void kernel_launch(void* const* d_in, const int* in_sizes, int n_in,
                              void* d_out, int out_size, void* d_ws, size_t ws_size,
                              hipStream_t stream) {
  const float* x      = (const float*)d_in[0];
  const float* x_demo = (const float*)d_in[1];
  const float* ftr    = (const float*)d_in[2];
  const float* h0     = (const float*)d_in[3];
  const float* Wx2e   = (const float*)d_in[4];
  const float* bx2e   = (const float*)d_in[5];
  const float* Wst    = (const float*)d_in[6];
  const float* bst    = (const float*)d_in[7];
  const float* Wm1a   = (const float*)d_in[8];
  const float* bm1a   = (const float*)d_in[9];
  const float* Wm1b   = (const float*)d_in[10];
  const float* bm1b   = (const float*)d_in[11];
  const float* Wm2a   = (const float*)d_in[12];
  const float* bm2a   = (const float*)d_in[13];
  const float* Wm2b   = (const float*)d_in[14];
  const float* bm2b   = (const float*)d_in[15];
  const float* Wa1    = (const float*)d_in[16];
  const float* ba1    = (const float*)d_in[17];
  const float* Wa2    = (const float*)d_in[18];
  const float* Wo1    = (const float*)d_in[19];
  const float* bo1    = (const float*)d_in[20];
  const float* Wo2    = (const float*)d_in[21];
  const float* Wih    = (const float*)d_in[22];
  const float* bih    = (const float*)d_in[23];
  const float* Whh    = (const float*)d_in[24];
  const float* bhh    = (const float*)d_in[25];
  float* out = (float*)d_out;

  char* ws = (char*)d_ws;
  bf16_t* F   = (bf16_t*)(ws);                             // 25165824 B
  bf16_t* WT  = (bf16_t*)(ws + 25165824);                  // 983040 B
  float*  bc  = (float*)(ws + 25165824 + 983040);          // 2560 B
  float*  G   = (float*)(ws + 25165824 + 983040 + 2560);   // 41943040 B

  prep_kernel<<<dim3((NTOT * KF + 255) / 256), dim3(256), 0, stream>>>(
      Wa1, ba1, Wo1, bo1, Wih, bih, WT, bc);
  encoder_kernel<<<dim3(BB * 16), dim3(64), 0, stream>>>(
      x, x_demo, ftr, Wm1a, bm1a, Wm1b, bm1b, Wm2a, bm2a, Wm2b, bm2b,
      Wx2e, bx2e, Wst, bst, F);
  gemm_kernel<<<dim3(BT / 128, NTOT / 128), dim3(256), 0, stream>>>(F, WT, bc, G);
  head_kernel<<<dim3(BT / 4), dim3(256), 0, stream>>>(G, Wa2, Wo2, out);
  gru_kernel<<<dim3(BB / 16), dim3(256), 0, stream>>>(G, h0, Whh, bhh, out);
}

// Round 8
// 240.641 us; speedup vs baseline: 1.0943x; 1.0943x over previous
//
#include <hip/hip_runtime.h>
#include <hip/hip_bf16.h>
#include <math.h>

// ---- problem constants ----
#define BB     256
#define TT     64
#define BT     (BB*TT)      // 16384 tokens
#define XD     44
#define XP     40
#define XS     10
#define HID    128
#define XEMB   32
#define NHID   8
#define NAG    10
#define NEDGE  90
#define GEMB   720          // NHID*NEDGE
#define KF     768          // padded fused feature dim
#define NTOT   640          // 128 (a) + 128 (o) + 384 (ih)

// F feature layout (v2): [0:32) xemb | [32:42) demo | [42] treat | [43:48) pad0 | [48:768) gemb
// G split: Gao[tok][256] (a/o heads), Gih[t][seq][384] (t-major for the GRU)

typedef __bf16  bf16_t;
typedef __bf16  bf16x4 __attribute__((ext_vector_type(4)));
typedef __bf16  bf16x8 __attribute__((ext_vector_type(8)));
typedef float   floatx4 __attribute__((ext_vector_type(4)));
typedef _Float16 half2_t __attribute__((ext_vector_type(2)));
typedef _Float16 half4_t __attribute__((ext_vector_type(4)));
typedef _Float16 half8_t __attribute__((ext_vector_type(8)));

__device__ __forceinline__ float rcp_fast(float x) { return __builtin_amdgcn_rcpf(x); }
__device__ __forceinline__ float sigmoid_fast(float v) { return rcp_fast(1.f + __expf(-v)); }
__device__ __forceinline__ float tanh_fast(float x) { return 1.f - 2.f * rcp_fast(1.f + __expf(2.f * x)); }
__device__ __forceinline__ float elu_fast(float v) { return v > 0.f ? v : __expf(v) - 1.f; }
__device__ __forceinline__ float fdot2f(half2_t a, half2_t b, float acc) {
  return __builtin_amdgcn_fdot2(a, b, acc, false);
}
__device__ __forceinline__ float dot8h(half8_t a, half8_t b, float acc) {
  acc = fdot2f(half2_t{a[0], a[1]}, half2_t{b[0], b[1]}, acc);
  acc = fdot2f(half2_t{a[2], a[3]}, half2_t{b[2], b[3]}, acc);
  acc = fdot2f(half2_t{a[4], a[5]}, half2_t{b[4], b[5]}, acc);
  acc = fdot2f(half2_t{a[6], a[7]}, half2_t{b[6], b[7]}, acc);
  return acc;
}
// LDS-only barrier: waits lgkmcnt(0) but leaves global loads/stores in flight.
__device__ __forceinline__ void lds_barrier() {
  asm volatile("s_waitcnt lgkmcnt(0)" ::: "memory");
  __builtin_amdgcn_s_barrier();
}

// ---------------------------------------------------------------------------
// Kernel 1: build Wcat^T (n-major, k-contiguous) bf16 + fused bias (fp32)
// ---------------------------------------------------------------------------
__global__ __launch_bounds__(256) void prep_kernel(
    const float* __restrict__ Wa1, const float* __restrict__ ba1,
    const float* __restrict__ Wo1, const float* __restrict__ bo1,
    const float* __restrict__ Wih, const float* __restrict__ bih,
    bf16_t* __restrict__ WT, float* __restrict__ bcat) {
  int idx = blockIdx.x * 256 + threadIdx.x;
  if (idx >= NTOT * KF) return;
  int n = idx / KF, k = idx - n * KF;
  float v = 0.f;
  if (n < 128) {                       // W_a1: a_in = [demo(10), gemb(720)]
    if (k >= 32 && k < 42)  v = Wa1[n * 730 + (k - 32)];
    else if (k >= 48)       v = Wa1[n * 730 + 10 + (k - 48)];
  } else if (n < 256) {                // W_o1: o_in = [xemb, demo, treat, gemb]
    int m = n - 128;
    if (k < 43)             v = Wo1[m * 763 + k];
    else if (k >= 48)       v = Wo1[m * 763 + 43 + (k - 48)];
  } else {                             // W_ih: rnn_in = [xemb(32), treat(1), gemb(720)]
    int m = n - 256;
    if (k < 32)             v = Wih[m * 753 + k];
    else if (k == 42)       v = Wih[m * 753 + 32];
    else if (k >= 48)       v = Wih[m * 753 + 33 + (k - 48)];
  }
  WT[n * KF + k] = (bf16_t)v;
  if (k == 0) {
    bcat[n] = (n < 128) ? ba1[n] : (n < 256 ? bo1[n - 128] : bih[n - 256]);
  }
}

// ---------------------------------------------------------------------------
// Kernel 2: encoder v3 — one wave per block, 4 tokens/block, packed-f16 dot2.
// ---------------------------------------------------------------------------
__global__ __launch_bounds__(64) void encoder_kernel(
    const float* __restrict__ x, const float* __restrict__ x_demo,
    const float* __restrict__ ftreat,
    const float* __restrict__ Wm1a, const float* __restrict__ bm1a,
    const float* __restrict__ Wm1b, const float* __restrict__ bm1b,
    const float* __restrict__ Wm2a, const float* __restrict__ bm2a,
    const float* __restrict__ Wm2b, const float* __restrict__ bm2b,
    const float* __restrict__ Wx2e, const float* __restrict__ bx2e,
    const float* __restrict__ Wst, const float* __restrict__ bst,
    bf16_t* __restrict__ F) {
  int blk = blockIdx.x;                 // 0..4095
  int b = blk >> 4, tc = blk & 15;      // batch, 4-token chunk
  int lane = threadIdx.x;

  __shared__ __align__(16) _Float16 h1sp[NAG * 8];
  __shared__ __align__(16) _Float16 w2aR[64];
  __shared__ __align__(16) _Float16 w2aS[64];
  __shared__ __align__(16) _Float16 w2bp[64];
  __shared__ float demoL[XS];

  if (lane < 8) {
    float4 v0 = *(const float4*)(Wm2a + lane * 16);
    float4 v1 = *(const float4*)(Wm2a + lane * 16 + 4);
    float4 v2 = *(const float4*)(Wm2a + lane * 16 + 8);
    float4 v3 = *(const float4*)(Wm2a + lane * 16 + 12);
    *(half8_t*)&w2aR[lane * 8] = half8_t{
        (_Float16)v0.x, (_Float16)v0.y, (_Float16)v0.z, (_Float16)v0.w,
        (_Float16)v1.x, (_Float16)v1.y, (_Float16)v1.z, (_Float16)v1.w};
    *(half8_t*)&w2aS[lane * 8] = half8_t{
        (_Float16)v2.x, (_Float16)v2.y, (_Float16)v2.z, (_Float16)v2.w,
        (_Float16)v3.x, (_Float16)v3.y, (_Float16)v3.z, (_Float16)v3.w};
    float4 u0 = *(const float4*)(Wm2b + lane * 8);
    float4 u1 = *(const float4*)(Wm2b + lane * 8 + 4);
    *(half8_t*)&w2bp[lane * 8] = half8_t{
        (_Float16)u0.x, (_Float16)u0.y, (_Float16)u0.z, (_Float16)u0.w,
        (_Float16)u1.x, (_Float16)u1.y, (_Float16)u1.z, (_Float16)u1.w};
  }
  if (lane < 10) {
    float s = bst[lane];
#pragma unroll
    for (int j = 0; j < 10; j++) s += x_demo[b * XS + j] * Wst[lane * 10 + j];
    demoL[lane] = s;
  }

  half4_t wA[8]; float bA[8];
  half8_t wB1[8]; float bB1[8];
  float bR[8], bG[8];
#pragma unroll
  for (int o = 0; o < 8; o++) {
    float4 v = *(const float4*)(Wm1a + o * 4);
    wA[o] = half4_t{(_Float16)v.x, (_Float16)v.y, (_Float16)v.z, (_Float16)v.w};
    bA[o] = bm1a[o];
    float4 w0 = *(const float4*)(Wm1b + o * 8);
    float4 w1 = *(const float4*)(Wm1b + o * 8 + 4);
    wB1[o] = half8_t{(_Float16)w0.x, (_Float16)w0.y, (_Float16)w0.z, (_Float16)w0.w,
                     (_Float16)w1.x, (_Float16)w1.y, (_Float16)w1.z, (_Float16)w1.w};
    bB1[o] = bm1b[o];
    bR[o] = bm2a[o];
    bG[o] = bm2b[o];
  }
  half4_t wX; float bX;
  {
    float4 v = *(const float4*)(Wx2e + (lane & 31) * 4);
    wX = half4_t{(_Float16)v.x, (_Float16)v.y, (_Float16)v.z, (_Float16)v.w};
    bX = bx2e[lane & 31];
  }
  __syncthreads();
  float demov = (lane >= 32 && lane < 42) ? demoL[lane - 32] : 0.f;

  for (int ti = 0; ti < 4; ti++) {
    int t = tc * 4 + ti;
    int tok = b * TT + t;
    const float* row = x + (size_t)(b * 65 + t) * XD;
    bf16_t* Frow = F + (size_t)tok * KF;

    if (lane < NAG) {
      float4 xa = *(const float4*)(row + lane * 4);
      half2_t x0{(_Float16)xa.x, (_Float16)xa.y};
      half2_t x1{(_Float16)xa.z, (_Float16)xa.w};
      float h1v[8];
#pragma unroll
      for (int o = 0; o < 8; o++) {
        float s = bA[o];
        s = fdot2f(x0, half2_t{wA[o][0], wA[o][1]}, s);
        s = fdot2f(x1, half2_t{wA[o][2], wA[o][3]}, s);
        h1v[o] = elu_fast(s);
      }
      half2_t e0{(_Float16)h1v[0], (_Float16)h1v[1]};
      half2_t e1{(_Float16)h1v[2], (_Float16)h1v[3]};
      half2_t e2{(_Float16)h1v[4], (_Float16)h1v[5]};
      half2_t e3{(_Float16)h1v[6], (_Float16)h1v[7]};
      half8_t hout;
#pragma unroll
      for (int o = 0; o < 8; o++) {
        float s = bB1[o];
        s = fdot2f(e0, half2_t{wB1[o][0], wB1[o][1]}, s);
        s = fdot2f(e1, half2_t{wB1[o][2], wB1[o][3]}, s);
        s = fdot2f(e2, half2_t{wB1[o][4], wB1[o][5]}, s);
        s = fdot2f(e3, half2_t{wB1[o][6], wB1[o][7]}, s);
        hout[o] = (_Float16)elu_fast(s);
      }
      *(half8_t*)&h1sp[lane * 8] = hout;
    }
    __syncthreads();

#pragma unroll
    for (int q = 0; q < 2; q++) {
      int e = lane + 64 * q;
      if (e < NEDGE) {
        int r = (e * 57) >> 9;               // e/9 for e<90
        int sd = e - 9 * r;
        sd += (sd >= r) ? 1 : 0;
        half8_t hr = *(const half8_t*)&h1sp[r * 8];
        half8_t hs = *(const half8_t*)&h1sp[sd * 8];
        float av[8];
#pragma unroll
        for (int o = 0; o < 8; o++) {
          half8_t wr8 = *(const half8_t*)&w2aR[o * 8];
          half8_t ws8 = *(const half8_t*)&w2aS[o * 8];
          float s = bR[o];
          s = dot8h(hr, wr8, s);
          s = dot8h(hs, ws8, s);
          av[o] = elu_fast(s);
        }
        half2_t a0{(_Float16)av[0], (_Float16)av[1]};
        half2_t a1{(_Float16)av[2], (_Float16)av[3]};
        half2_t a2{(_Float16)av[4], (_Float16)av[5]};
        half2_t a3{(_Float16)av[6], (_Float16)av[7]};
        union { bf16_t h[8]; uint4 u; } pk;
#pragma unroll
        for (int o = 0; o < 8; o++) {
          half8_t wb8 = *(const half8_t*)&w2bp[o * 8];
          float s = bG[o];
          s = fdot2f(a0, half2_t{wb8[0], wb8[1]}, s);
          s = fdot2f(a1, half2_t{wb8[2], wb8[3]}, s);
          s = fdot2f(a2, half2_t{wb8[4], wb8[5]}, s);
          s = fdot2f(a3, half2_t{wb8[6], wb8[7]}, s);
          pk.h[o] = (bf16_t)elu_fast(s);
        }
        *(uint4*)(Frow + 48 + e * 8) = pk.u;
      }
    }

    float4 xe = *(const float4*)(row + XP);
    if (lane < 32) {
      float s = bX;
      s = fdot2f(half2_t{(_Float16)xe.x, (_Float16)xe.y}, half2_t{wX[0], wX[1]}, s);
      s = fdot2f(half2_t{(_Float16)xe.z, (_Float16)xe.w}, half2_t{wX[2], wX[3]}, s);
      Frow[lane] = (bf16_t)s;
    } else if (lane < 42) {
      Frow[lane] = (bf16_t)demov;
    } else if (lane == 42) {
      Frow[42] = (bf16_t)ftreat[b * 65 + t];
    } else if (lane < 48) {
      Frow[lane] = (bf16_t)0.f;
    }
    __syncthreads();
  }
}

// ---------------------------------------------------------------------------
// Kernel 3: [Gao|Gih] = F[16384,768] @ WT^T + bcat  (bf16 MFMA, fp32 acc)
// cols <256 -> Gao[tok][256]; cols >=256 -> Gih[t][seq][384] (t-major).
// Branch is block-uniform (n0 multiple of 128). Lane-group stores stay
// 64B-contiguous in both layouts.
// ---------------------------------------------------------------------------
__global__ __launch_bounds__(256) void gemm_kernel(
    const bf16_t* __restrict__ F, const bf16_t* __restrict__ WT,
    const float* __restrict__ bcat, float* __restrict__ Gao,
    float* __restrict__ Gih) {
  __shared__ __align__(16) bf16_t As[128 * 32];
  __shared__ __align__(16) bf16_t Bs[128 * 32];

  int tid  = threadIdx.x;
  int lane = tid & 63;
  int wv   = tid >> 6;
  int wr   = wv >> 1, wc = wv & 1;
  int m0 = blockIdx.x * 128, n0 = blockIdx.y * 128;

  floatx4 acc[4][4];
#pragma unroll
  for (int i = 0; i < 4; i++)
#pragma unroll
    for (int j = 0; j < 4; j++) acc[i][j] = floatx4{0.f, 0.f, 0.f, 0.f};

  int c0 = tid, c1 = tid + 256;
  int r0 = c0 >> 2, p0 = c0 & 3;
  int r1 = c1 >> 2, p1 = c1 & 3;
  int qr = lane >> 4;
  int lr = lane & 15;

  for (int k0 = 0; k0 < KF; k0 += 32) {
    uint4 a0 = *(const uint4*)(F  + (size_t)(m0 + r0) * KF + k0 + p0 * 8);
    uint4 a1 = *(const uint4*)(F  + (size_t)(m0 + r1) * KF + k0 + p1 * 8);
    uint4 b0 = *(const uint4*)(WT + (size_t)(n0 + r0) * KF + k0 + p0 * 8);
    uint4 b1 = *(const uint4*)(WT + (size_t)(n0 + r1) * KF + k0 + p1 * 8);
    __syncthreads();
    ((uint4*)As)[c0] = a0; ((uint4*)As)[c1] = a1;
    ((uint4*)Bs)[c0] = b0; ((uint4*)Bs)[c1] = b1;
    __syncthreads();

    bf16x8 af[4], bf[4];
#pragma unroll
    for (int i = 0; i < 4; i++) {
      af[i] = *(const bf16x8*)(As + (wr * 64 + i * 16 + lr) * 32 + qr * 8);
      bf[i] = *(const bf16x8*)(Bs + (wc * 64 + i * 16 + lr) * 32 + qr * 8);
    }
#pragma unroll
    for (int i = 0; i < 4; i++)
#pragma unroll
      for (int j = 0; j < 4; j++)
        acc[i][j] = __builtin_amdgcn_mfma_f32_16x16x32_bf16(af[i], bf[j], acc[i][j], 0, 0, 0);
  }

#pragma unroll
  for (int i = 0; i < 4; i++) {
#pragma unroll
    for (int j = 0; j < 4; j++) {
      int col = n0 + wc * 64 + j * 16 + lr;
      float bv = bcat[col];
#pragma unroll
      for (int r = 0; r < 4; r++) {
        int row = m0 + wr * 64 + i * 16 + qr * 4 + r;
        float val = acc[i][j][r] + bv;
        if (n0 < 256) {
          Gao[(size_t)row * 256 + col] = val;
        } else {
          int tt = row & 63, bq = row >> 6;
          Gih[(size_t)(tt * 256 + bq) * 384 + (col - 256)] = val;
        }
      }
    }
  }
}

// ---------------------------------------------------------------------------
// Kernel 4: heads — a_out / y_out (one wave per token)
// ---------------------------------------------------------------------------
__global__ __launch_bounds__(256) void head_kernel(
    const float* __restrict__ Gao, const float* __restrict__ Wa2,
    const float* __restrict__ Wo2, float* __restrict__ out) {
  int wid  = (blockIdx.x * 256 + threadIdx.x) >> 6;
  int lane = threadIdx.x & 63;
  const float* g = Gao + (size_t)wid * 256;
  float sa = fmaxf(g[lane], 0.f) * Wa2[lane] + fmaxf(g[lane + 64], 0.f) * Wa2[lane + 64];
  float sy = fmaxf(g[128 + lane], 0.f) * Wo2[lane] + fmaxf(g[192 + lane], 0.f) * Wo2[lane + 64];
#pragma unroll
  for (int off = 32; off > 0; off >>= 1) {
    sa += __shfl_down(sa, off, 64);
    sy += __shfl_down(sy, off, 64);
  }
  if (lane == 0) {
    out[(size_t)wid * 130 + 0] = sa;
    out[(size_t)wid * 130 + 1] = sy;
  }
}

// ---------------------------------------------------------------------------
// Kernel 5: GRU v5 — MFMA-batched, coalesced t-major gi, depth-2 prefetch.
// 16 blocks x 512 threads (8 waves); block owns 16 sequences.
// Wave w owns units [w*16,(w+1)*16) of all 3 gates: 12 MFMA/wave/step.
// gi reads from Gih[t][seq][384]: 4-lane groups hit contiguous 64B lines.
// Unroll t by 2 with two gi register sets (gA/gB): each set is reloaded for
// t+2 right after its last use -> ~2 steps (~1200cy) of latency cover, no
// register rotation. One lgkm-only barrier/step; out stores stay in flight.
// ---------------------------------------------------------------------------
__global__ __launch_bounds__(512, 1) void gru_kernel(
    const float* __restrict__ Gih, const float* __restrict__ h0,
    const float* __restrict__ Whh, const float* __restrict__ bhh,
    float* __restrict__ out) {
  int tid  = threadIdx.x;
  int w    = tid >> 6;          // wave 0..7
  int lane = tid & 63;
  int l15  = lane & 15;         // sequence within block
  int quad = lane >> 4;
  int b0   = blockIdx.x * 16;
  int s    = b0 + l15;          // this lane's sequence
  int jb   = w * 16 + quad * 4; // unit base (0..124)

  __shared__ __align__(16) bf16_t hT[2][16 * 136];   // [buf][seq*136 + unit]

  // A-fragments of Whh: gate g, rows g*128 + w*16 + l15, k = ks*32 + quad*8 + j
  bf16x8 afrag[3][4];
#pragma unroll
  for (int g = 0; g < 3; g++) {
    const float* wrow = Whh + (size_t)(g * 128 + w * 16 + l15) * HID + quad * 8;
#pragma unroll
    for (int ks = 0; ks < 4; ks++) {
      float4 a = *(const float4*)(wrow + ks * 32);
      float4 b = *(const float4*)(wrow + ks * 32 + 4);
      afrag[g][ks] = bf16x8{
          (bf16_t)a.x, (bf16_t)a.y, (bf16_t)a.z, (bf16_t)a.w,
          (bf16_t)b.x, (bf16_t)b.y, (bf16_t)b.z, (bf16_t)b.w};
    }
  }
  floatx4 biasv[3];
#pragma unroll
  for (int g = 0; g < 3; g++) biasv[g] = *(const floatx4*)(bhh + g * 128 + jb);
  floatx4 hprev = *(const floatx4*)(h0 + (size_t)s * HID + jb);

  // initial h tile (threads 0..255: seq-major bf16)
  if (tid < 256) {
    int sq = tid >> 4, u = (tid & 15) * 8;
    const float* hr = h0 + (size_t)(b0 + sq) * HID + u;
    float4 a = *(const float4*)hr;
    float4 b = *(const float4*)(hr + 4);
    *(bf16x8*)&hT[0][sq * 136 + u] = bf16x8{
        (bf16_t)a.x, (bf16_t)a.y, (bf16_t)a.z, (bf16_t)a.w,
        (bf16_t)b.x, (bf16_t)b.y, (bf16_t)b.z, (bf16_t)b.w};
  }

  const float* gbase = Gih + (size_t)s * 384 + jb;   // + t*98304 + g*128
  floatx4 gA[3], gB[3];
#pragma unroll
  for (int g = 0; g < 3; g++) gA[g] = *(const floatx4*)(gbase + g * 128);
#pragma unroll
  for (int g = 0; g < 3; g++) gB[g] = *(const floatx4*)(gbase + 98304 + g * 128);
  __syncthreads();

#define GRU_STEP(T, GREG)                                                      \
  {                                                                            \
    const bf16_t* hb = &hT[(T) & 1][l15 * 136 + quad * 8];                     \
    bf16x8 bfrag[4];                                                           \
    _Pragma("unroll")                                                          \
    for (int ks = 0; ks < 4; ks++) bfrag[ks] = *(const bf16x8*)(hb + ks * 32); \
    floatx4 acc[3];                                                            \
    _Pragma("unroll")                                                          \
    for (int g = 0; g < 3; g++) acc[g] = biasv[g];                             \
    _Pragma("unroll")                                                          \
    for (int ks = 0; ks < 4; ks++)                                             \
      _Pragma("unroll")                                                        \
      for (int g = 0; g < 3; g++)                                              \
        acc[g] = __builtin_amdgcn_mfma_f32_16x16x32_bf16(                      \
            afrag[g][ks], bfrag[ks], acc[g], 0, 0, 0);                         \
    floatx4 hn;                                                                \
    _Pragma("unroll")                                                          \
    for (int r = 0; r < 4; r++) {                                              \
      float rr = sigmoid_fast(GREG[0][r] + acc[0][r]);                         \
      float zz = sigmoid_fast(GREG[1][r] + acc[1][r]);                         \
      float nn = tanh_fast(GREG[2][r] + rr * acc[2][r]);                       \
      hn[r] = (1.f - zz) * nn + zz * hprev[r];                                 \
    }                                                                          \
    hprev = hn;                                                                \
    *(bf16x4*)&hT[((T) + 1) & 1][l15 * 136 + jb] =                             \
        bf16x4{(bf16_t)hn[0], (bf16_t)hn[1], (bf16_t)hn[2], (bf16_t)hn[3]};    \
    float* ob = out + ((size_t)s * TT + (T)) * 130 + 2 + jb;                   \
    *(float2*)ob = float2{hn[0], hn[1]};                                       \
    *(float2*)(ob + 2) = float2{hn[2], hn[3]};                                 \
    if ((T) + 2 < TT) {                                                        \
      const float* gp = gbase + (size_t)((T) + 2) * 98304;                     \
      _Pragma("unroll")                                                        \
      for (int g = 0; g < 3; g++) GREG[g] = *(const floatx4*)(gp + g * 128);   \
    }                                                                          \
    lds_barrier();                                                             \
  }

  for (int t = 0; t < TT; t += 2) {
    GRU_STEP(t, gA);
    GRU_STEP(t + 1, gB);
  }
#undef GRU_STEP
}

// ---------------------------------------------------------------------------
extern "C" void kernel_launch(void* const* d_in, const int* in_sizes, int n_in,
                              void* d_out, int out_size, void* d_ws, size_t ws_size,
                              hipStream_t stream) {
  const float* x      = (const float*)d_in[0];
  const float* x_demo = (const float*)d_in[1];
  const float* ftr    = (const float*)d_in[2];
  const float* h0     = (const float*)d_in[3];
  const float* Wx2e   = (const float*)d_in[4];
  const float* bx2e   = (const float*)d_in[5];
  const float* Wst    = (const float*)d_in[6];
  const float* bst    = (const float*)d_in[7];
  const float* Wm1a   = (const float*)d_in[8];
  const float* bm1a   = (const float*)d_in[9];
  const float* Wm1b   = (const float*)d_in[10];
  const float* bm1b   = (const float*)d_in[11];
  const float* Wm2a   = (const float*)d_in[12];
  const float* bm2a   = (const float*)d_in[13];
  const float* Wm2b   = (const float*)d_in[14];
  const float* bm2b   = (const float*)d_in[15];
  const float* Wa1    = (const float*)d_in[16];
  const float* ba1    = (const float*)d_in[17];
  const float* Wa2    = (const float*)d_in[18];
  const float* Wo1    = (const float*)d_in[19];
  const float* bo1    = (const float*)d_in[20];
  const float* Wo2    = (const float*)d_in[21];
  const float* Wih    = (const float*)d_in[22];
  const float* bih    = (const float*)d_in[23];
  const float* Whh    = (const float*)d_in[24];
  const float* bhh    = (const float*)d_in[25];
  float* out = (float*)d_out;

  char* ws = (char*)d_ws;
  bf16_t* F   = (bf16_t*)(ws);                                  // 25165824 B
  bf16_t* WT  = (bf16_t*)(ws + 25165824);                       // 983040 B
  float*  bc  = (float*)(ws + 25165824 + 983040);               // 2560 B
  float*  Gao = (float*)(ws + 25165824 + 983040 + 2560);        // 16777216 B
  float*  Gih = (float*)(ws + 25165824 + 983040 + 2560 + 16777216); // 25165824 B

  prep_kernel<<<dim3((NTOT * KF + 255) / 256), dim3(256), 0, stream>>>(
      Wa1, ba1, Wo1, bo1, Wih, bih, WT, bc);
  encoder_kernel<<<dim3(BB * 16), dim3(64), 0, stream>>>(
      x, x_demo, ftr, Wm1a, bm1a, Wm1b, bm1b, Wm2a, bm2a, Wm2b, bm2b,
      Wx2e, bx2e, Wst, bst, F);
  gemm_kernel<<<dim3(BT / 128, NTOT / 128), dim3(256), 0, stream>>>(F, WT, bc, Gao, Gih);
  head_kernel<<<dim3(BT / 4), dim3(256), 0, stream>>>(Gao, Wa2, Wo2, out);
  gru_kernel<<<dim3(BB / 16), dim3(512), 0, stream>>>(Gih, h0, Whh, bhh, out);
}

// Round 9
// 235.969 us; speedup vs baseline: 1.1160x; 1.0198x over previous
//
#include <hip/hip_runtime.h>
#include <hip/hip_bf16.h>
#include <math.h>

// ---- problem constants ----
#define BB     256
#define TT     64
#define BT     (BB*TT)      // 16384 tokens
#define XD     44
#define XP     40
#define XS     10
#define HID    128
#define XEMB   32
#define NHID   8
#define NAG    10
#define NEDGE  90
#define GEMB   720          // NHID*NEDGE
#define KF     768          // padded fused feature dim
#define NTOT   640          // 128 (a) + 128 (o) + 384 (ih)

// F feature layout: [0:32) xemb | [32:42) demo | [42] treat | [43:48) pad0 | [48:768) gemb
// Gih[t][seq][384] (t-major for the GRU). Heads fused into gemm epilogue.

typedef __bf16  bf16_t;
typedef __bf16  bf16x4 __attribute__((ext_vector_type(4)));
typedef __bf16  bf16x8 __attribute__((ext_vector_type(8)));
typedef float   floatx4 __attribute__((ext_vector_type(4)));
typedef _Float16 half2_t __attribute__((ext_vector_type(2)));
typedef _Float16 half4_t __attribute__((ext_vector_type(4)));
typedef _Float16 half8_t __attribute__((ext_vector_type(8)));

__device__ __forceinline__ float rcp_fast(float x) { return __builtin_amdgcn_rcpf(x); }
__device__ __forceinline__ float sigmoid_fast(float v) { return rcp_fast(1.f + __expf(-v)); }
__device__ __forceinline__ float tanh_fast(float x) { return 1.f - 2.f * rcp_fast(1.f + __expf(2.f * x)); }
__device__ __forceinline__ float elu_fast(float v) { return v > 0.f ? v : __expf(v) - 1.f; }
__device__ __forceinline__ float fdot2f(half2_t a, half2_t b, float acc) {
  return __builtin_amdgcn_fdot2(a, b, acc, false);
}
__device__ __forceinline__ float dot8h(half8_t a, half8_t b, float acc) {
  acc = fdot2f(half2_t{a[0], a[1]}, half2_t{b[0], b[1]}, acc);
  acc = fdot2f(half2_t{a[2], a[3]}, half2_t{b[2], b[3]}, acc);
  acc = fdot2f(half2_t{a[4], a[5]}, half2_t{b[4], b[5]}, acc);
  acc = fdot2f(half2_t{a[6], a[7]}, half2_t{b[6], b[7]}, acc);
  return acc;
}
// LDS-only barrier: waits lgkmcnt(0) but leaves global loads/stores in flight.
__device__ __forceinline__ void lds_barrier() {
  asm volatile("s_waitcnt lgkmcnt(0)" ::: "memory");
  __builtin_amdgcn_s_barrier();
}
// async global->LDS, 16B per lane; lds dest = wave-uniform base + lane*16
__device__ __forceinline__ void gl16(const bf16_t* g, bf16_t* l) {
  __builtin_amdgcn_global_load_lds(
      (const __attribute__((address_space(1))) void*)g,
      (__attribute__((address_space(3))) void*)l, 16, 0, 0);
}

// ---------------------------------------------------------------------------
// Kernel 1: build Wcat^T (n-major, k-contiguous) bf16 + fused bias (fp32)
// ---------------------------------------------------------------------------
__global__ __launch_bounds__(256) void prep_kernel(
    const float* __restrict__ Wa1, const float* __restrict__ ba1,
    const float* __restrict__ Wo1, const float* __restrict__ bo1,
    const float* __restrict__ Wih, const float* __restrict__ bih,
    bf16_t* __restrict__ WT, float* __restrict__ bcat) {
  int idx = blockIdx.x * 256 + threadIdx.x;
  if (idx >= NTOT * KF) return;
  int n = idx / KF, k = idx - n * KF;
  float v = 0.f;
  if (n < 128) {                       // W_a1: a_in = [demo(10), gemb(720)]
    if (k >= 32 && k < 42)  v = Wa1[n * 730 + (k - 32)];
    else if (k >= 48)       v = Wa1[n * 730 + 10 + (k - 48)];
  } else if (n < 256) {                // W_o1: o_in = [xemb, demo, treat, gemb]
    int m = n - 128;
    if (k < 43)             v = Wo1[m * 763 + k];
    else if (k >= 48)       v = Wo1[m * 763 + 43 + (k - 48)];
  } else {                             // W_ih: rnn_in = [xemb(32), treat(1), gemb(720)]
    int m = n - 256;
    if (k < 32)             v = Wih[m * 753 + k];
    else if (k == 42)       v = Wih[m * 753 + 32];
    else if (k >= 48)       v = Wih[m * 753 + 33 + (k - 48)];
  }
  WT[n * KF + k] = (bf16_t)v;
  if (k == 0) {
    bcat[n] = (n < 128) ? ba1[n] : (n < 256 ? bo1[n - 128] : bih[n - 256]);
  }
}

// ---------------------------------------------------------------------------
// Kernel 2: encoder v3 — one wave per block, 4 tokens/block, packed-f16 dot2.
// ---------------------------------------------------------------------------
__global__ __launch_bounds__(64) void encoder_kernel(
    const float* __restrict__ x, const float* __restrict__ x_demo,
    const float* __restrict__ ftreat,
    const float* __restrict__ Wm1a, const float* __restrict__ bm1a,
    const float* __restrict__ Wm1b, const float* __restrict__ bm1b,
    const float* __restrict__ Wm2a, const float* __restrict__ bm2a,
    const float* __restrict__ Wm2b, const float* __restrict__ bm2b,
    const float* __restrict__ Wx2e, const float* __restrict__ bx2e,
    const float* __restrict__ Wst, const float* __restrict__ bst,
    bf16_t* __restrict__ F) {
  int blk = blockIdx.x;                 // 0..4095
  int b = blk >> 4, tc = blk & 15;      // batch, 4-token chunk
  int lane = threadIdx.x;

  __shared__ __align__(16) _Float16 h1sp[NAG * 8];
  __shared__ __align__(16) _Float16 w2aR[64];
  __shared__ __align__(16) _Float16 w2aS[64];
  __shared__ __align__(16) _Float16 w2bp[64];
  __shared__ float demoL[XS];

  if (lane < 8) {
    float4 v0 = *(const float4*)(Wm2a + lane * 16);
    float4 v1 = *(const float4*)(Wm2a + lane * 16 + 4);
    float4 v2 = *(const float4*)(Wm2a + lane * 16 + 8);
    float4 v3 = *(const float4*)(Wm2a + lane * 16 + 12);
    *(half8_t*)&w2aR[lane * 8] = half8_t{
        (_Float16)v0.x, (_Float16)v0.y, (_Float16)v0.z, (_Float16)v0.w,
        (_Float16)v1.x, (_Float16)v1.y, (_Float16)v1.z, (_Float16)v1.w};
    *(half8_t*)&w2aS[lane * 8] = half8_t{
        (_Float16)v2.x, (_Float16)v2.y, (_Float16)v2.z, (_Float16)v2.w,
        (_Float16)v3.x, (_Float16)v3.y, (_Float16)v3.z, (_Float16)v3.w};
    float4 u0 = *(const float4*)(Wm2b + lane * 8);
    float4 u1 = *(const float4*)(Wm2b + lane * 8 + 4);
    *(half8_t*)&w2bp[lane * 8] = half8_t{
        (_Float16)u0.x, (_Float16)u0.y, (_Float16)u0.z, (_Float16)u0.w,
        (_Float16)u1.x, (_Float16)u1.y, (_Float16)u1.z, (_Float16)u1.w};
  }
  if (lane < 10) {
    float s = bst[lane];
#pragma unroll
    for (int j = 0; j < 10; j++) s += x_demo[b * XS + j] * Wst[lane * 10 + j];
    demoL[lane] = s;
  }

  half4_t wA[8]; float bA[8];
  half8_t wB1[8]; float bB1[8];
  float bR[8], bG[8];
#pragma unroll
  for (int o = 0; o < 8; o++) {
    float4 v = *(const float4*)(Wm1a + o * 4);
    wA[o] = half4_t{(_Float16)v.x, (_Float16)v.y, (_Float16)v.z, (_Float16)v.w};
    bA[o] = bm1a[o];
    float4 w0 = *(const float4*)(Wm1b + o * 8);
    float4 w1 = *(const float4*)(Wm1b + o * 8 + 4);
    wB1[o] = half8_t{(_Float16)w0.x, (_Float16)w0.y, (_Float16)w0.z, (_Float16)w0.w,
                     (_Float16)w1.x, (_Float16)w1.y, (_Float16)w1.z, (_Float16)w1.w};
    bB1[o] = bm1b[o];
    bR[o] = bm2a[o];
    bG[o] = bm2b[o];
  }
  half4_t wX; float bX;
  {
    float4 v = *(const float4*)(Wx2e + (lane & 31) * 4);
    wX = half4_t{(_Float16)v.x, (_Float16)v.y, (_Float16)v.z, (_Float16)v.w};
    bX = bx2e[lane & 31];
  }
  __syncthreads();
  float demov = (lane >= 32 && lane < 42) ? demoL[lane - 32] : 0.f;

  for (int ti = 0; ti < 4; ti++) {
    int t = tc * 4 + ti;
    int tok = b * TT + t;
    const float* row = x + (size_t)(b * 65 + t) * XD;
    bf16_t* Frow = F + (size_t)tok * KF;

    if (lane < NAG) {
      float4 xa = *(const float4*)(row + lane * 4);
      half2_t x0{(_Float16)xa.x, (_Float16)xa.y};
      half2_t x1{(_Float16)xa.z, (_Float16)xa.w};
      float h1v[8];
#pragma unroll
      for (int o = 0; o < 8; o++) {
        float s = bA[o];
        s = fdot2f(x0, half2_t{wA[o][0], wA[o][1]}, s);
        s = fdot2f(x1, half2_t{wA[o][2], wA[o][3]}, s);
        h1v[o] = elu_fast(s);
      }
      half2_t e0{(_Float16)h1v[0], (_Float16)h1v[1]};
      half2_t e1{(_Float16)h1v[2], (_Float16)h1v[3]};
      half2_t e2{(_Float16)h1v[4], (_Float16)h1v[5]};
      half2_t e3{(_Float16)h1v[6], (_Float16)h1v[7]};
      half8_t hout;
#pragma unroll
      for (int o = 0; o < 8; o++) {
        float s = bB1[o];
        s = fdot2f(e0, half2_t{wB1[o][0], wB1[o][1]}, s);
        s = fdot2f(e1, half2_t{wB1[o][2], wB1[o][3]}, s);
        s = fdot2f(e2, half2_t{wB1[o][4], wB1[o][5]}, s);
        s = fdot2f(e3, half2_t{wB1[o][6], wB1[o][7]}, s);
        hout[o] = (_Float16)elu_fast(s);
      }
      *(half8_t*)&h1sp[lane * 8] = hout;
    }
    __syncthreads();

#pragma unroll
    for (int q = 0; q < 2; q++) {
      int e = lane + 64 * q;
      if (e < NEDGE) {
        int r = (e * 57) >> 9;               // e/9 for e<90
        int sd = e - 9 * r;
        sd += (sd >= r) ? 1 : 0;
        half8_t hr = *(const half8_t*)&h1sp[r * 8];
        half8_t hs = *(const half8_t*)&h1sp[sd * 8];
        float av[8];
#pragma unroll
        for (int o = 0; o < 8; o++) {
          half8_t wr8 = *(const half8_t*)&w2aR[o * 8];
          half8_t ws8 = *(const half8_t*)&w2aS[o * 8];
          float s = bR[o];
          s = dot8h(hr, wr8, s);
          s = dot8h(hs, ws8, s);
          av[o] = elu_fast(s);
        }
        half2_t a0{(_Float16)av[0], (_Float16)av[1]};
        half2_t a1{(_Float16)av[2], (_Float16)av[3]};
        half2_t a2{(_Float16)av[4], (_Float16)av[5]};
        half2_t a3{(_Float16)av[6], (_Float16)av[7]};
        union { bf16_t h[8]; uint4 u; } pk;
#pragma unroll
        for (int o = 0; o < 8; o++) {
          half8_t wb8 = *(const half8_t*)&w2bp[o * 8];
          float s = bG[o];
          s = fdot2f(a0, half2_t{wb8[0], wb8[1]}, s);
          s = fdot2f(a1, half2_t{wb8[2], wb8[3]}, s);
          s = fdot2f(a2, half2_t{wb8[4], wb8[5]}, s);
          s = fdot2f(a3, half2_t{wb8[6], wb8[7]}, s);
          pk.h[o] = (bf16_t)elu_fast(s);
        }
        *(uint4*)(Frow + 48 + e * 8) = pk.u;
      }
    }

    float4 xe = *(const float4*)(row + XP);
    if (lane < 32) {
      float s = bX;
      s = fdot2f(half2_t{(_Float16)xe.x, (_Float16)xe.y}, half2_t{wX[0], wX[1]}, s);
      s = fdot2f(half2_t{(_Float16)xe.z, (_Float16)xe.w}, half2_t{wX[2], wX[3]}, s);
      Frow[lane] = (bf16_t)s;
    } else if (lane < 42) {
      Frow[lane] = (bf16_t)demov;
    } else if (lane == 42) {
      Frow[42] = (bf16_t)ftreat[b * 65 + t];
    } else if (lane < 48) {
      Frow[lane] = (bf16_t)0.f;
    }
    __syncthreads();
  }
}

// ---------------------------------------------------------------------------
// Kernel 3: gemm v2 — global_load_lds(16B) staging + fused heads.
// n0>=256: Gih[t][seq][384] t-major store.
// n0<256:  head reduction: out[tok*130 + {0,1}] = relu(row)·W{a,o}2.
// ---------------------------------------------------------------------------
__global__ __launch_bounds__(256) void gemm_kernel(
    const bf16_t* __restrict__ F, const bf16_t* __restrict__ WT,
    const float* __restrict__ bcat, const float* __restrict__ Wa2,
    const float* __restrict__ Wo2, float* __restrict__ Gih,
    float* __restrict__ out) {
  __shared__ __align__(16) bf16_t As[128 * 32];
  __shared__ __align__(16) bf16_t Bs[128 * 32];
  __shared__ float hred[128];

  int tid  = threadIdx.x;
  int lane = tid & 63;
  int wv   = tid >> 6;
  int wr   = wv >> 1, wc = wv & 1;
  int m0 = blockIdx.x * 128, n0 = blockIdx.y * 128;

  floatx4 acc[4][4];
#pragma unroll
  for (int i = 0; i < 4; i++)
#pragma unroll
    for (int j = 0; j < 4; j++) acc[i][j] = floatx4{0.f, 0.f, 0.f, 0.f};

  int qr = lane >> 4;
  int lr = lane & 15;

  // staging: wave wv owns rows [wv*32, wv*32+32) of both As and Bs.
  // call c covers 16 rows: lane l -> row base+l/4, 16B chunk kp=l&3.
  const bf16_t* gA = F  + (size_t)(m0 + wv * 32 + (lane >> 2)) * KF + (lane & 3) * 8;
  const bf16_t* gB = WT + (size_t)(n0 + wv * 32 + (lane >> 2)) * KF + (lane & 3) * 8;
  bf16_t* lA = As + (wv * 32) * 32;
  bf16_t* lB = Bs + (wv * 32) * 32;

  for (int k0 = 0; k0 < KF; k0 += 32) {
    __syncthreads();                    // prev MFMA reads done before overwrite
    gl16(gA + k0,             lA);
    gl16(gA + 16 * KF + k0,   lA + 16 * 32);
    gl16(gB + k0,             lB);
    gl16(gB + 16 * KF + k0,   lB + 16 * 32);
    __syncthreads();                    // vmcnt(0) drain -> staging visible

    bf16x8 af[4], bf[4];
#pragma unroll
    for (int i = 0; i < 4; i++) {
      af[i] = *(const bf16x8*)(As + (wr * 64 + i * 16 + lr) * 32 + qr * 8);
      bf[i] = *(const bf16x8*)(Bs + (wc * 64 + i * 16 + lr) * 32 + qr * 8);
    }
#pragma unroll
    for (int i = 0; i < 4; i++)
#pragma unroll
      for (int j = 0; j < 4; j++)
        acc[i][j] = __builtin_amdgcn_mfma_f32_16x16x32_bf16(af[i], bf[j], acc[i][j], 0, 0, 0);
  }

  if (n0 >= 256) {
    // ih columns -> Gih[t][seq][384]
#pragma unroll
    for (int i = 0; i < 4; i++) {
#pragma unroll
      for (int j = 0; j < 4; j++) {
        int col = n0 + wc * 64 + j * 16 + lr;
        float bv = bcat[col];
#pragma unroll
        for (int r = 0; r < 4; r++) {
          int row = m0 + wr * 64 + i * 16 + qr * 4 + r;
          int tt = row & 63, bq = row >> 6;
          Gih[(size_t)(tt * 256 + bq) * 384 + (col - 256)] = acc[i][j][r] + bv;
        }
      }
    }
  } else {
    // fused head: per-row sum over 128 cols of relu(val)*w2[colh]
    const float* w2 = (n0 == 0) ? Wa2 : Wo2;
    int head = (n0 == 0) ? 0 : 1;
    float v[4][4];
#pragma unroll
    for (int i = 0; i < 4; i++)
#pragma unroll
      for (int r = 0; r < 4; r++) v[i][r] = 0.f;
#pragma unroll
    for (int j = 0; j < 4; j++) {
      int colh = wc * 64 + j * 16 + lr;          // 0..127 within head
      float bv = bcat[n0 + colh];
      float ww = w2[colh];
#pragma unroll
      for (int i = 0; i < 4; i++)
#pragma unroll
        for (int r = 0; r < 4; r++)
          v[i][r] += fmaxf(acc[i][j][r] + bv, 0.f) * ww;
    }
    // reduce over the 16 lanes of this quad (lr = 0..15)
#pragma unroll
    for (int off = 8; off > 0; off >>= 1)
#pragma unroll
      for (int i = 0; i < 4; i++)
#pragma unroll
        for (int r = 0; r < 4; r++)
          v[i][r] += __shfl_down(v[i][r], off, 64);
    __syncthreads();                    // re-use LDS region boundary
    if (lr == 0 && wc == 0) {
#pragma unroll
      for (int i = 0; i < 4; i++)
#pragma unroll
        for (int r = 0; r < 4; r++)
          hred[wr * 64 + i * 16 + qr * 4 + r] = v[i][r];
    }
    __syncthreads();
    if (lr == 0 && wc == 1) {
#pragma unroll
      for (int i = 0; i < 4; i++)
#pragma unroll
        for (int r = 0; r < 4; r++) {
          int row = wr * 64 + i * 16 + qr * 4 + r;
          out[(size_t)(m0 + row) * 130 + head] = hred[row] + v[i][r];
        }
    }
  }
}

// ---------------------------------------------------------------------------
// Kernel 5: GRU v5 — MFMA-batched, coalesced t-major gi, depth-2 prefetch.
// (unchanged from R8)
// ---------------------------------------------------------------------------
__global__ __launch_bounds__(512, 1) void gru_kernel(
    const float* __restrict__ Gih, const float* __restrict__ h0,
    const float* __restrict__ Whh, const float* __restrict__ bhh,
    float* __restrict__ out) {
  int tid  = threadIdx.x;
  int w    = tid >> 6;          // wave 0..7
  int lane = tid & 63;
  int l15  = lane & 15;         // sequence within block
  int quad = lane >> 4;
  int b0   = blockIdx.x * 16;
  int s    = b0 + l15;          // this lane's sequence
  int jb   = w * 16 + quad * 4; // unit base (0..124)

  __shared__ __align__(16) bf16_t hT[2][16 * 136];   // [buf][seq*136 + unit]

  bf16x8 afrag[3][4];
#pragma unroll
  for (int g = 0; g < 3; g++) {
    const float* wrow = Whh + (size_t)(g * 128 + w * 16 + l15) * HID + quad * 8;
#pragma unroll
    for (int ks = 0; ks < 4; ks++) {
      float4 a = *(const float4*)(wrow + ks * 32);
      float4 b = *(const float4*)(wrow + ks * 32 + 4);
      afrag[g][ks] = bf16x8{
          (bf16_t)a.x, (bf16_t)a.y, (bf16_t)a.z, (bf16_t)a.w,
          (bf16_t)b.x, (bf16_t)b.y, (bf16_t)b.z, (bf16_t)b.w};
    }
  }
  floatx4 biasv[3];
#pragma unroll
  for (int g = 0; g < 3; g++) biasv[g] = *(const floatx4*)(bhh + g * 128 + jb);
  floatx4 hprev = *(const floatx4*)(h0 + (size_t)s * HID + jb);

  if (tid < 256) {
    int sq = tid >> 4, u = (tid & 15) * 8;
    const float* hr = h0 + (size_t)(b0 + sq) * HID + u;
    float4 a = *(const float4*)hr;
    float4 b = *(const float4*)(hr + 4);
    *(bf16x8*)&hT[0][sq * 136 + u] = bf16x8{
        (bf16_t)a.x, (bf16_t)a.y, (bf16_t)a.z, (bf16_t)a.w,
        (bf16_t)b.x, (bf16_t)b.y, (bf16_t)b.z, (bf16_t)b.w};
  }

  const float* gbase = Gih + (size_t)s * 384 + jb;   // + t*98304 + g*128
  floatx4 gA[3], gB[3];
#pragma unroll
  for (int g = 0; g < 3; g++) gA[g] = *(const floatx4*)(gbase + g * 128);
#pragma unroll
  for (int g = 0; g < 3; g++) gB[g] = *(const floatx4*)(gbase + 98304 + g * 128);
  __syncthreads();

#define GRU_STEP(T, GREG)                                                      \
  {                                                                            \
    const bf16_t* hb = &hT[(T) & 1][l15 * 136 + quad * 8];                     \
    bf16x8 bfrag[4];                                                           \
    _Pragma("unroll")                                                          \
    for (int ks = 0; ks < 4; ks++) bfrag[ks] = *(const bf16x8*)(hb + ks * 32); \
    floatx4 acc[3];                                                            \
    _Pragma("unroll")                                                          \
    for (int g = 0; g < 3; g++) acc[g] = biasv[g];                             \
    _Pragma("unroll")                                                          \
    for (int ks = 0; ks < 4; ks++)                                             \
      _Pragma("unroll")                                                        \
      for (int g = 0; g < 3; g++)                                              \
        acc[g] = __builtin_amdgcn_mfma_f32_16x16x32_bf16(                      \
            afrag[g][ks], bfrag[ks], acc[g], 0, 0, 0);                         \
    floatx4 hn;                                                                \
    _Pragma("unroll")                                                          \
    for (int r = 0; r < 4; r++) {                                              \
      float rr = sigmoid_fast(GREG[0][r] + acc[0][r]);                         \
      float zz = sigmoid_fast(GREG[1][r] + acc[1][r]);                         \
      float nn = tanh_fast(GREG[2][r] + rr * acc[2][r]);                       \
      hn[r] = (1.f - zz) * nn + zz * hprev[r];                                 \
    }                                                                          \
    hprev = hn;                                                                \
    *(bf16x4*)&hT[((T) + 1) & 1][l15 * 136 + jb] =                             \
        bf16x4{(bf16_t)hn[0], (bf16_t)hn[1], (bf16_t)hn[2], (bf16_t)hn[3]};    \
    float* ob = out + ((size_t)s * TT + (T)) * 130 + 2 + jb;                   \
    *(float2*)ob = float2{hn[0], hn[1]};                                       \
    *(float2*)(ob + 2) = float2{hn[2], hn[3]};                                 \
    if ((T) + 2 < TT) {                                                        \
      const float* gp = gbase + (size_t)((T) + 2) * 98304;                     \
      _Pragma("unroll")                                                        \
      for (int g = 0; g < 3; g++) GREG[g] = *(const floatx4*)(gp + g * 128);   \
    }                                                                          \
    lds_barrier();                                                             \
  }

  for (int t = 0; t < TT; t += 2) {
    GRU_STEP(t, gA);
    GRU_STEP(t + 1, gB);
  }
#undef GRU_STEP
}

// ---------------------------------------------------------------------------
extern "C" void kernel_launch(void* const* d_in, const int* in_sizes, int n_in,
                              void* d_out, int out_size, void* d_ws, size_t ws_size,
                              hipStream_t stream) {
  const float* x      = (const float*)d_in[0];
  const float* x_demo = (const float*)d_in[1];
  const float* ftr    = (const float*)d_in[2];
  const float* h0     = (const float*)d_in[3];
  const float* Wx2e   = (const float*)d_in[4];
  const float* bx2e   = (const float*)d_in[5];
  const float* Wst    = (const float*)d_in[6];
  const float* bst    = (const float*)d_in[7];
  const float* Wm1a   = (const float*)d_in[8];
  const float* bm1a   = (const float*)d_in[9];
  const float* Wm1b   = (const float*)d_in[10];
  const float* bm1b   = (const float*)d_in[11];
  const float* Wm2a   = (const float*)d_in[12];
  const float* bm2a   = (const float*)d_in[13];
  const float* Wm2b   = (const float*)d_in[14];
  const float* bm2b   = (const float*)d_in[15];
  const float* Wa1    = (const float*)d_in[16];
  const float* ba1    = (const float*)d_in[17];
  const float* Wa2    = (const float*)d_in[18];
  const float* Wo1    = (const float*)d_in[19];
  const float* bo1    = (const float*)d_in[20];
  const float* Wo2    = (const float*)d_in[21];
  const float* Wih    = (const float*)d_in[22];
  const float* bih    = (const float*)d_in[23];
  const float* Whh    = (const float*)d_in[24];
  const float* bhh    = (const float*)d_in[25];
  float* out = (float*)d_out;

  char* ws = (char*)d_ws;
  bf16_t* F   = (bf16_t*)(ws);                             // 25165824 B
  bf16_t* WT  = (bf16_t*)(ws + 25165824);                  // 983040 B
  float*  bc  = (float*)(ws + 25165824 + 983040);          // 2560 B
  float*  Gih = (float*)(ws + 25165824 + 983040 + 2560);   // 25165824 B

  prep_kernel<<<dim3((NTOT * KF + 255) / 256), dim3(256), 0, stream>>>(
      Wa1, ba1, Wo1, bo1, Wih, bih, WT, bc);
  encoder_kernel<<<dim3(BB * 16), dim3(64), 0, stream>>>(
      x, x_demo, ftr, Wm1a, bm1a, Wm1b, bm1b, Wm2a, bm2a, Wm2b, bm2b,
      Wx2e, bx2e, Wst, bst, F);
  gemm_kernel<<<dim3(BT / 128, NTOT / 128), dim3(256), 0, stream>>>(
      F, WT, bc, Wa2, Wo2, Gih, out);
  gru_kernel<<<dim3(BB / 16), dim3(512), 0, stream>>>(Gih, h0, Whh, bhh, out);
}